// Round 6
// baseline (13258.391 us; speedup 1.0000x reference)
//
#include <hip/hip_runtime.h>
#include <hip/hip_bf16.h>
#include <stdint.h>

#define BATCH 4096
#define TT    80
#define EMB   100
#define UNITS 512
#define K0P   128

typedef unsigned short ushort;
typedef unsigned char uchar;
typedef __bf16 bf16x8 __attribute__((ext_vector_type(8)));
typedef float f32x4 __attribute__((ext_vector_type(4)));
typedef uint32_t u32x4 __attribute__((ext_vector_type(4)));

// tiled element offset: 16-row x 32-col tiles, chunk-major inside
// [rt][kt][chunk(4)][rowlo(16)][8 elems]  (KT = K/32)
#define TOFF(r, k, KT)                                                  \
  ((((size_t)((r) >> 4) * (KT) + ((k) >> 5)) << 9) +                    \
   ((((k) >> 3) & 3) << 7) + (((r) & 15) << 3) + ((k) & 7))

// ---------------- threefry2x32 (JAX partitionable mode, verified r1) ------
__device__ __forceinline__ uint32_t rotl32(uint32_t x, uint32_t r) {
  return (x << r) | (x >> (32u - r));
}
__device__ __forceinline__ void tf_round4(uint32_t& x0, uint32_t& x1,
                                          int r0, int r1, int r2, int r3) {
  x0 += x1; x1 = rotl32(x1, r0); x1 ^= x0;
  x0 += x1; x1 = rotl32(x1, r1); x1 ^= x0;
  x0 += x1; x1 = rotl32(x1, r2); x1 ^= x0;
  x0 += x1; x1 = rotl32(x1, r3); x1 ^= x0;
}
__device__ __forceinline__ void tf2x32(uint32_t k0, uint32_t k1,
                                       uint32_t x0, uint32_t x1,
                                       uint32_t& y0, uint32_t& y1) {
  uint32_t k2 = k0 ^ k1 ^ 0x1BD11BDAu;
  x0 += k0; x1 += k1;
  tf_round4(x0, x1, 13, 15, 26, 6);  x0 += k1; x1 += k2 + 1u;
  tf_round4(x0, x1, 17, 29, 16, 24); x0 += k2; x1 += k0 + 2u;
  tf_round4(x0, x1, 13, 15, 26, 6);  x0 += k0; x1 += k1 + 3u;
  tf_round4(x0, x1, 17, 29, 16, 24); x0 += k1; x1 += k2 + 4u;
  tf_round4(x0, x1, 13, 15, 26, 6);  x0 += k2; x1 += k0 + 5u;
  y0 = x0; y1 = x1;
}
__device__ __forceinline__ int keepbit(uint32_t u) {
  float f = __uint_as_float((u >> 9) | 0x3F800000u) - 1.0f;
  return f < 0.8f ? 1 : 0;
}
__device__ __forceinline__ ushort f2bf(float f) {
  uint32_t u = __float_as_uint(f);
  uint32_t r = (u + 0x7FFFu + ((u >> 16) & 1u)) >> 16;
  return (ushort)r;
}
__device__ __forceinline__ float bf2f(ushort u) {
  return __uint_as_float(((uint32_t)u) << 16);
}
__device__ __forceinline__ float fast_tanh(float x) {
  const float ax = fabsf(x);
  const float t = __expf(-2.f * ax);
  const float r = (1.f - t) / (1.f + t);
  return copysignf(r, x);
}

// ---------------- byte masks: 0xFF = keep, 0x00 = drop (r4-proven) --------
__global__ __launch_bounds__(256) void masksB(uchar* __restrict__ m0B,
                                              uchar* __restrict__ m1B) {
  uint32_t k0a, k0b, k1a, k1b;
  tf2x32(0u, 42u, 0u, 0u, k0a, k0b);
  tf2x32(0u, 42u, 0u, 1u, k1a, k1b);
  const int T0 = 4 * BATCH * K0P;
  const int T1 = 4 * BATCH * UNITS;
  for (int i = blockIdx.x * blockDim.x + threadIdx.x; i < T0 + T1;
       i += gridDim.x * blockDim.x) {
    if (i < T0) {
      const int g = i >> 19, b = (i >> 7) & 4095, k = i & 127;
      uchar v = 0;
      if (k < EMB) {
        uint32_t y0, y1;
        tf2x32(k0a, k0b, 0u, (uint32_t)(g * (BATCH * EMB) + b * EMB + k), y0, y1);
        v = keepbit(y0 ^ y1) ? 0xFFu : 0u;
      }
      m0B[i] = v;
    } else {
      const int j = i - T0;
      const int g = j >> 21, b = (j >> 9) & 4095, k = j & 511;
      uint32_t y0, y1;
      tf2x32(k1a, k1b, 0u, (uint32_t)(g * (BATCH * UNITS) + b * UNITS + k), y0, y1);
      m1B[j] = keepbit(y0 ^ y1) ? 0xFFu : 0u;
    }
  }
}

// weight convert+transpose+scale: src[K][2048] f32 -> linear [2048][Kpad] bf16
__global__ __launch_bounds__(256) void convT(const float* __restrict__ src,
                                             ushort* __restrict__ dst,
                                             int Ksrc, int Kpad, float scale) {
  __shared__ float t[32][33];
  const int n0 = blockIdx.x * 32, kk0 = blockIdx.y * 32;
  const int tx = threadIdx.x & 31, ty = threadIdx.x >> 5;
#pragma unroll
  for (int r = ty; r < 32; r += 8) {
    const int k = kk0 + r;
    t[r][tx] = (k < Ksrc) ? src[(size_t)k * 2048 + n0 + tx] : 0.f;
  }
  __syncthreads();
#pragma unroll
  for (int r = ty; r < 32; r += 8)
    dst[(size_t)(n0 + r) * Kpad + kk0 + tx] = f2bf(scale * t[tx][r]);
}

// linear [2048][K] bf16 -> chunk-major tiled
__global__ __launch_bounds__(256) void retileB(const ushort* __restrict__ lin,
                                               ushort* __restrict__ til, int K) {
  const int id = blockIdx.x * 256 + threadIdx.x;  // one 8-elem chunk each
  const int r = id / (K >> 3);
  const int kc = id % (K >> 3);
  bf16x8 v = *(const bf16x8*)(lin + (size_t)r * K + kc * 8);
  *(bf16x8*)(til + TOFF(r, kc * 8, K >> 5)) = v;
}

// initial X prep (tiled): step 0 -> XA, step 1 -> XB
__global__ __launch_bounds__(256) void xprep2(const int* __restrict__ inputs,
                                              const float* __restrict__ embed,
                                              ushort* __restrict__ XA,
                                              ushort* __restrict__ XB) {
  const int i = blockIdx.x * 256 + threadIdx.x;  // 2 * 4096 * 16
  const int s = i >> 16, rem = i & 65535;
  const int b = rem >> 4, kc = rem & 15;
  ushort* X = s ? XB : XA;
  const int idx = inputs[b * TT + s];
  ushort v[8];
#pragma unroll
  for (int j = 0; j < 8; j++) {
    const int kk = kc * 8 + j;
    v[j] = (kk < EMB) ? f2bf(embed[(size_t)idx * EMB + kk]) : (ushort)0;
  }
  *(bf16x8*)(X + TOFF(b, kc * 8, 4)) = *(bf16x8*)v;
}

__device__ __forceinline__ void gload16(const void* g, void* l) {
  __builtin_amdgcn_global_load_lds(
      (const __attribute__((address_space(1))) unsigned int*)g,
      (__attribute__((address_space(3))) unsigned int*)l, 16, 0, 0);
}

// ---------------- fused step: l1(t) + l0(t+1), 128x128 tiles --------------
// Block: 128 rows x [4 gates][32 h]. Waves 2x2 (wr: 64 rows, wc: 16 h).
// acc[fi][g]; col(lane) = bh0 + wc*16 + fr; row = bm0 + wr*64 + fi*16 + kq*4+jj
__global__ __launch_bounds__(256) void fused_step(
    int nl1, int nl0,
    const ushort* __restrict__ h0m, const ushort* __restrict__ h1p,
    ushort* __restrict__ h1o, float* __restrict__ c1f,
    const ushort* __restrict__ W1T, const ushort* __restrict__ U1T,
    const float* __restrict__ b1, const uchar* __restrict__ m1B,
    const ushort* __restrict__ Xc, const ushort* __restrict__ h0p,
    ushort* __restrict__ h0o, float* __restrict__ c0f,
    const ushort* __restrict__ W0T, const ushort* __restrict__ U0T,
    const float* __restrict__ b0, const uchar* __restrict__ m0B,
    int tprep, const int* __restrict__ inputs, const float* __restrict__ embed,
    ushort* __restrict__ Xprep) {
  __shared__ __align__(16) ushort smem[16384];  // 2 bufs x (A 4096 + B 4096)
  const int bid = blockIdx.x, tid = threadIdx.x;
  const bool isl1 = bid < nl1;
  const int lbid = isl1 ? bid : bid - nl1;
  const int cid = (lbid & 7) * 64 + (lbid >> 3);  // XCD-chunked
  const int mblk = cid >> 4, nblk = cid & 15;
  const int bm0 = mblk * 128, bh0 = nblk * 32;
  const int rtb = bm0 >> 4;
  const int nb2 = nblk * 2;
  const int w = tid >> 6, l = tid & 63;
  const int wr = w >> 1, wc = w & 1;
  const int fr = l & 15, kq = l >> 4;

  const ushort *A1, *B1, *A2, *B2;
  const uchar* mB;
  const float* bias;
  float* cb;
  ushort* hout;
  int KTA1, S1, K1;
  if (isl1) {
    A1 = h0m; B1 = W1T; A2 = h1p; B2 = U1T; mB = m1B; bias = b1;
    cb = c1f; hout = h1o; KTA1 = 16; S1 = 16; K1 = 512;
  } else {
    A1 = Xc; B1 = W0T; A2 = h0p; B2 = U0T; mB = m0B; bias = b0;
    cb = c0f; hout = h0o; KTA1 = 4; S1 = 4; K1 = 128;
  }
  const int S = S1 + 16;

  f32x4 acc[4][4] = {};
  f32x4 cold[4];

  // prologue: stage s=0 into buf0
#pragma unroll
  for (int c2 = 0; c2 < 2; c2++) {
    const int rt = w + c2 * 4;
    gload16(A1 + ((size_t)(rtb + rt) * KTA1) * 512 + l * 8, smem + rt * 512);
    const int nt = (rt >> 1) * 32 + nb2 + (rt & 1);
    gload16(B1 + ((size_t)nt * KTA1) * 512 + l * 8, smem + 4096 + rt * 512);
  }
  __syncthreads();

#pragma unroll 1
  for (int s = 0; s < S; s++) {
    ushort* cur = smem + (s & 1) * 8192;
    ushort* nxt = smem + ((s & 1) ^ 1) * 8192;

    // mask loads for this step (issue early; L2-resident after first pass)
    uint2 md[4][4];
    const bool masked = s < S1;
    if (masked) {
      const int kb = s * 32 + kq * 8;
#pragma unroll
      for (int fi = 0; fi < 4; fi++) {
        const int row = bm0 + wr * 64 + fi * 16 + fr;
        const uchar* mrow = mB + (size_t)row * K1 + kb;
#pragma unroll
        for (int g = 0; g < 4; g++)
          md[fi][g] = *(const uint2*)(mrow + (size_t)g * (BATCH * K1));
      }
    }

    // stage s+1
    if (s + 1 < S) {
      const bool m2 = (s + 1 < S1);
      const ushort* A = m2 ? A1 : A2;
      const ushort* B = m2 ? B1 : B2;
      const int KT = m2 ? KTA1 : 16;
      const int kt = m2 ? (s + 1) : (s + 1 - S1);
#pragma unroll
      for (int c2 = 0; c2 < 2; c2++) {
        const int rt = w + c2 * 4;
        gload16(A + ((size_t)(rtb + rt) * KT + kt) * 512 + l * 8,
                nxt + rt * 512);
        const int nt = (rt >> 1) * 32 + nb2 + (rt & 1);
        gload16(B + ((size_t)nt * KT + kt) * 512 + l * 8,
                nxt + 4096 + rt * 512);
      }
    }
    // c-state prefetch near the end (latency hidden under last k-steps)
    if (s == S - 3) {
      const float* cbase = cb + ((size_t)cid * 256 + tid) * 16;
#pragma unroll
      for (int q = 0; q < 4; q++) cold[q] = *(const f32x4*)(cbase + q * 4);
    }

    // frags: lane-linear (conflict-free) ds_read_b128
    u32x4 af[4];
    bf16x8 bfr[4];
#pragma unroll
    for (int fi = 0; fi < 4; fi++)
      af[fi] = *(const u32x4*)&cur[(wr * 4 + fi) * 512 + l * 8];
#pragma unroll
    for (int g = 0; g < 4; g++)
      bfr[g] = *(const bf16x8*)&cur[4096 + (g * 2 + wc) * 512 + l * 8];

    if (masked) {
#pragma unroll
      for (int fi = 0; fi < 4; fi++) {
#pragma unroll
        for (int g = 0; g < 4; g++) {
          const uint2 m = md[fi][g];
          u32x4 ua = af[fi];
          ua.x &= __builtin_amdgcn_perm(m.x, m.x, 0x01010000u);
          ua.y &= __builtin_amdgcn_perm(m.x, m.x, 0x03030202u);
          ua.z &= __builtin_amdgcn_perm(m.y, m.y, 0x01010000u);
          ua.w &= __builtin_amdgcn_perm(m.y, m.y, 0x03030202u);
          acc[fi][g] = __builtin_amdgcn_mfma_f32_16x16x32_bf16(
              __builtin_bit_cast(bf16x8, ua), bfr[g], acc[fi][g], 0, 0, 0);
        }
      }
    } else {
#pragma unroll
      for (int fi = 0; fi < 4; fi++)
#pragma unroll
        for (int g = 0; g < 4; g++)
          acc[fi][g] = __builtin_amdgcn_mfma_f32_16x16x32_bf16(
              __builtin_bit_cast(bf16x8, af[fi]), bfr[g], acc[fi][g], 0, 0, 0);
    }
    __syncthreads();
  }

  // ---- fused gates epilogue: c in slot-blob, h via LDS transpose ----
  float bi, bfv, bg, bo;
  {
    const int h = bh0 + wc * 16 + fr;
    bi = bias[h]; bfv = bias[512 + h]; bg = bias[1024 + h]; bo = bias[1536 + h];
  }
  f32x4 cnew[4];
#pragma unroll
  for (int fi = 0; fi < 4; fi++) {
#pragma unroll
    for (int jj = 0; jj < 4; jj++) {
      const float zi = acc[fi][0][jj] + bi;
      const float zf = acc[fi][1][jj] + bfv;
      const float zg = acc[fi][2][jj] + bg;
      const float zo = acc[fi][3][jj] + bo;
      const float iv = 1.f / (1.f + __expf(-zi));
      const float fv = 1.f / (1.f + __expf(-zf));
      const float gv = fast_tanh(zg);
      const float ov = 1.f / (1.f + __expf(-zo));
      const float cn = fv * cold[fi][jj] + iv * gv;
      cnew[fi][jj] = cn;
      const float hn = ov * fast_tanh(cn);
      smem[(wr * 64 + fi * 16 + kq * 4 + jj) * 32 + wc * 16 + fr] = f2bf(hn);
    }
  }
  {
    float* cbase = cb + ((size_t)cid * 256 + tid) * 16;
#pragma unroll
    for (int q = 0; q < 4; q++) *(f32x4*)(cbase + q * 4) = cnew[q];
  }
  __syncthreads();

  // coalesced tiled h writeback: 128 rows x 32 cols = 512 chunks
#pragma unroll
  for (int c2 = 0; c2 < 2; c2++) {
    const int u = tid * 2 + c2;
    const int r = u >> 2, kc = u & 3;
    *(bf16x8*)(hout + TOFF(bm0 + r, bh0 + kc * 8, 16)) =
        *(const bf16x8*)&smem[r * 32 + kc * 8];
  }

  // X prep for step tprep (l0 blocks with nblk==0 only; 32 blocks x 128 rows)
  if (!isl1 && nblk == 0 && tprep >= 0) {
#pragma unroll 1
    for (int u2 = 0; u2 < 8; u2++) {
      const int id = tid * 8 + u2;       // 2048 chunks: 128 rows x 16 kc
      const int rl = id >> 4, kc = id & 15;
      const int row = bm0 + rl;
      const int idx = inputs[row * TT + tprep];
      ushort v[8];
#pragma unroll
      for (int j = 0; j < 8; j++) {
        const int kk = kc * 8 + j;
        v[j] = (kk < EMB) ? f2bf(embed[(size_t)idx * EMB + kk]) : (ushort)0;
      }
      *(bf16x8*)(Xprep + TOFF(row, kc * 8, 4)) = *(bf16x8*)v;
    }
  }
}

// ---------------- final projection (tiled h read) -------------------------
__global__ __launch_bounds__(256) void out_kernel(const ushort* __restrict__ h1b,
                                                  const float* __restrict__ Wout,
                                                  const float* __restrict__ bout,
                                                  float* __restrict__ out) {
  const int wid = (blockIdx.x * 256 + threadIdx.x) >> 6;
  const int lane = threadIdx.x & 63;
  if (wid >= BATCH) return;
  const int rt = wid >> 4, rl = wid & 15;
  const int kt = lane >> 2, ch = lane & 3;
  const ushort* p = h1b + (((size_t)(rt * 16 + kt)) << 9) + (ch << 7) + (rl << 3);
  const int kbase = kt * 32 + ch * 8;
  float s = 0.f;
#pragma unroll
  for (int e = 0; e < 8; e++) s += bf2f(p[e]) * Wout[kbase + e];
  for (int off = 32; off; off >>= 1) s += __shfl_down(s, off, 64);
  if (lane == 0) out[wid] = 1.f / (1.f + __expf(-(s + bout[0])));
}

// --------------------------------------------------------------------------
extern "C" void kernel_launch(void* const* d_in, const int* in_sizes, int n_in,
                              void* d_out, int out_size, void* d_ws, size_t ws_size,
                              hipStream_t stream) {
  const int* inputs = (const int*)d_in[0];
  const float* embed = (const float*)d_in[1];
  const float* W0 = (const float*)d_in[2];
  const float* U0 = (const float*)d_in[3];
  const float* b0 = (const float*)d_in[4];
  const float* W1 = (const float*)d_in[5];
  const float* U1 = (const float*)d_in[6];
  const float* b1 = (const float*)d_in[7];
  const float* Wout = (const float*)d_in[8];
  const float* bout = (const float*)d_in[9];
  float* out = (float*)d_out;

  char* ws = (char*)d_ws;
  const size_t MB = 1 << 20;
  float* c0f   = (float*)(ws);              //  8 MB (zero)
  float* c1f   = (float*)(ws + 8 * MB);     //  8 MB (zero)
  ushort* h0b1 = (ushort*)(ws + 16 * MB);   //  4 MB (zero)
  ushort* h1b1 = (ushort*)(ws + 20 * MB);   //  4 MB (zero)
  ushort* h0b0 = (ushort*)(ws + 24 * MB);   //  4 MB
  ushort* h1b0 = (ushort*)(ws + 28 * MB);   //  4 MB
  ushort* X0   = (ushort*)(ws + 32 * MB);   //  1 MB
  ushort* X1   = (ushort*)(ws + 33 * MB);   //  1 MB
  ushort* X2   = (ushort*)(ws + 34 * MB);   //  1 MB
  ushort* W0T  = (ushort*)(ws + 35 * MB);   //  0.5 MB tiled [2048][128]
  ushort* U0T  = (ushort*)(ws + 36 * MB);   //  2 MB   tiled [2048][512]
  ushort* W1T  = (ushort*)(ws + 38 * MB);   //  2 MB
  ushort* U1T  = (ushort*)(ws + 40 * MB);   //  2 MB
  ushort* tmp  = (ushort*)(ws + 42 * MB);   //  2 MB   linear scratch
  uchar* m0B   = (uchar*)(ws + 44 * MB);    //  2 MB   [4][4096][128]
  uchar* m1B   = (uchar*)(ws + 46 * MB);    //  8 MB   [4][4096][512]

  ushort* h0b[2] = {h0b0, h0b1};
  ushort* h1b[2] = {h1b0, h1b1};
  ushort* X[3] = {X0, X1, X2};

  hipMemsetAsync(ws, 0, 24 * MB, stream);   // c0f, c1f, h0b1, h1b1

  masksB<<<8192, 256, 0, stream>>>(m0B, m1B);
  {
    dim3 g0(2048 / 32, K0P / 32), g1(2048 / 32, UNITS / 32);
    convT<<<g0, 256, 0, stream>>>(W0, tmp, EMB, K0P, 1.25f);
    retileB<<<(2048 * K0P / 8) / 256, 256, 0, stream>>>(tmp, W0T, K0P);
    convT<<<g1, 256, 0, stream>>>(U0, tmp, UNITS, UNITS, 1.0f);
    retileB<<<(2048 * UNITS / 8) / 256, 256, 0, stream>>>(tmp, U0T, UNITS);
    convT<<<g1, 256, 0, stream>>>(W1, tmp, UNITS, UNITS, 1.25f);
    retileB<<<(2048 * UNITS / 8) / 256, 256, 0, stream>>>(tmp, W1T, UNITS);
    convT<<<g1, 256, 0, stream>>>(U1, tmp, UNITS, UNITS, 1.0f);
    retileB<<<(2048 * UNITS / 8) / 256, 256, 0, stream>>>(tmp, U1T, UNITS);
  }
  xprep2<<<512, 256, 0, stream>>>(inputs, embed, X0, X1);

  // prologue: l0(t=0) only; h_prev = h0b[1] (zeros); preps X[2] (t=2)
  fused_step<<<512, 256, 0, stream>>>(
      0, 512, h0b[1], h1b[1], h1b[0], c1f, W1T, U1T, b1, m1B,
      X[0], h0b[1], h0b[0], c0f, W0T, U0T, b0, m0B,
      2, inputs, embed, X[2]);

  for (int k = 0; k < TT; k++) {
    const int p = k & 1;
    const int nl0 = (k < TT - 1) ? 512 : 0;
    const int tp = (k + 3 < TT) ? (k + 3) : -1;
    fused_step<<<512 + nl0, 256, 0, stream>>>(
        512, nl0,
        h0b[p], h1b[p ^ 1], h1b[p], c1f, W1T, U1T, b1, m1B,
        X[(k + 1) % 3], h0b[p], h0b[p ^ 1], c0f, W0T, U0T, b0, m0B,
        tp, inputs, embed, X[k % 3]);
  }

  // final h1 written at t=79 -> h1b[1]
  out_kernel<<<BATCH * 64 / 256, 256, 0, stream>>>(h1b[1], Wout, bout, out);
}

// Round 7
// 6389.783 us; speedup vs baseline: 2.0749x; 2.0749x over previous
//
#include <hip/hip_runtime.h>
#include <hip/hip_bf16.h>
#include <stdint.h>

#define BATCH 4096
#define TT    80
#define EMB   100
#define UNITS 512
#define K0P   128

typedef unsigned short ushort;
typedef unsigned char uchar;
typedef __bf16 bf16x8 __attribute__((ext_vector_type(8)));
typedef float f32x4 __attribute__((ext_vector_type(4)));
typedef uint32_t u32x4 __attribute__((ext_vector_type(4)));

// tiled element offset: 16-row x 32-col tiles, chunk-major inside
// [rt][kt][chunk(4)][rowlo(16)][8 elems]  (KT = K/32)
#define TOFF(r, k, KT)                                                  \
  ((((size_t)((r) >> 4) * (KT) + ((k) >> 5)) << 9) +                    \
   ((((k) >> 3) & 3) << 7) + (((r) & 15) << 3) + ((k) & 7))

// ---------------- threefry2x32 (JAX partitionable mode, verified r1) ------
__device__ __forceinline__ uint32_t rotl32(uint32_t x, uint32_t r) {
  return (x << r) | (x >> (32u - r));
}
__device__ __forceinline__ void tf_round4(uint32_t& x0, uint32_t& x1,
                                          int r0, int r1, int r2, int r3) {
  x0 += x1; x1 = rotl32(x1, r0); x1 ^= x0;
  x0 += x1; x1 = rotl32(x1, r1); x1 ^= x0;
  x0 += x1; x1 = rotl32(x1, r2); x1 ^= x0;
  x0 += x1; x1 = rotl32(x1, r3); x1 ^= x0;
}
__device__ __forceinline__ void tf2x32(uint32_t k0, uint32_t k1,
                                       uint32_t x0, uint32_t x1,
                                       uint32_t& y0, uint32_t& y1) {
  uint32_t k2 = k0 ^ k1 ^ 0x1BD11BDAu;
  x0 += k0; x1 += k1;
  tf_round4(x0, x1, 13, 15, 26, 6);  x0 += k1; x1 += k2 + 1u;
  tf_round4(x0, x1, 17, 29, 16, 24); x0 += k2; x1 += k0 + 2u;
  tf_round4(x0, x1, 13, 15, 26, 6);  x0 += k0; x1 += k1 + 3u;
  tf_round4(x0, x1, 17, 29, 16, 24); x0 += k1; x1 += k2 + 4u;
  tf_round4(x0, x1, 13, 15, 26, 6);  x0 += k2; x1 += k0 + 5u;
  y0 = x0; y1 = x1;
}
__device__ __forceinline__ int keepbit(uint32_t u) {
  float f = __uint_as_float((u >> 9) | 0x3F800000u) - 1.0f;
  return f < 0.8f ? 1 : 0;
}
__device__ __forceinline__ ushort f2bf(float f) {
  uint32_t u = __float_as_uint(f);
  uint32_t r = (u + 0x7FFFu + ((u >> 16) & 1u)) >> 16;
  return (ushort)r;
}
__device__ __forceinline__ float bf2f(ushort u) {
  return __uint_as_float(((uint32_t)u) << 16);
}
__device__ __forceinline__ float fast_tanh(float x) {
  const float ax = fabsf(x);
  const float t = __expf(-2.f * ax);
  const float r = (1.f - t) / (1.f + t);
  return copysignf(r, x);
}

// ---------------- byte masks: 0xFF = keep, 0x00 = drop (r4-proven) --------
__global__ __launch_bounds__(256) void masksB(uchar* __restrict__ m0B,
                                              uchar* __restrict__ m1B) {
  uint32_t k0a, k0b, k1a, k1b;
  tf2x32(0u, 42u, 0u, 0u, k0a, k0b);
  tf2x32(0u, 42u, 0u, 1u, k1a, k1b);
  const int T0 = 4 * BATCH * K0P;
  const int T1 = 4 * BATCH * UNITS;
  for (int i = blockIdx.x * blockDim.x + threadIdx.x; i < T0 + T1;
       i += gridDim.x * blockDim.x) {
    if (i < T0) {
      const int g = i >> 19, b = (i >> 7) & 4095, k = i & 127;
      uchar v = 0;
      if (k < EMB) {
        uint32_t y0, y1;
        tf2x32(k0a, k0b, 0u, (uint32_t)(g * (BATCH * EMB) + b * EMB + k), y0, y1);
        v = keepbit(y0 ^ y1) ? 0xFFu : 0u;
      }
      m0B[i] = v;
    } else {
      const int j = i - T0;
      const int g = j >> 21, b = (j >> 9) & 4095, k = j & 511;
      uint32_t y0, y1;
      tf2x32(k1a, k1b, 0u, (uint32_t)(g * (BATCH * UNITS) + b * UNITS + k), y0, y1);
      m1B[j] = keepbit(y0 ^ y1) ? 0xFFu : 0u;
    }
  }
}

// weight convert+transpose+scale: src[K][2048] f32 -> linear [2048][Kpad] bf16
__global__ __launch_bounds__(256) void convT(const float* __restrict__ src,
                                             ushort* __restrict__ dst,
                                             int Ksrc, int Kpad, float scale) {
  __shared__ float t[32][33];
  const int n0 = blockIdx.x * 32, kk0 = blockIdx.y * 32;
  const int tx = threadIdx.x & 31, ty = threadIdx.x >> 5;
#pragma unroll
  for (int r = ty; r < 32; r += 8) {
    const int k = kk0 + r;
    t[r][tx] = (k < Ksrc) ? src[(size_t)k * 2048 + n0 + tx] : 0.f;
  }
  __syncthreads();
#pragma unroll
  for (int r = ty; r < 32; r += 8)
    dst[(size_t)(n0 + r) * Kpad + kk0 + tx] = f2bf(scale * t[tx][r]);
}

// linear [2048][K] bf16 -> chunk-major tiled
__global__ __launch_bounds__(256) void retileB(const ushort* __restrict__ lin,
                                               ushort* __restrict__ til, int K) {
  const int id = blockIdx.x * 256 + threadIdx.x;
  const int r = id / (K >> 3);
  const int kc = id % (K >> 3);
  bf16x8 v = *(const bf16x8*)(lin + (size_t)r * K + kc * 8);
  *(bf16x8*)(til + TOFF(r, kc * 8, K >> 5)) = v;
}

// initial X prep (tiled): step 0 -> XA, step 1 -> XB
__global__ __launch_bounds__(256) void xprep2(const int* __restrict__ inputs,
                                              const float* __restrict__ embed,
                                              ushort* __restrict__ XA,
                                              ushort* __restrict__ XB) {
  const int i = blockIdx.x * 256 + threadIdx.x;
  const int s = i >> 16, rem = i & 65535;
  const int b = rem >> 4, kc = rem & 15;
  ushort* X = s ? XB : XA;
  const int idx = inputs[b * TT + s];
  ushort v[8];
#pragma unroll
  for (int j = 0; j < 8; j++) {
    const int kk = kc * 8 + j;
    v[j] = (kk < EMB) ? f2bf(embed[(size_t)idx * EMB + kk]) : (ushort)0;
  }
  *(bf16x8*)(X + TOFF(b, kc * 8, 4)) = *(bf16x8*)v;
}

__device__ __forceinline__ void gload16(const void* g, void* l) {
  __builtin_amdgcn_global_load_lds(
      (const __attribute__((address_space(1))) unsigned int*)g,
      (__attribute__((address_space(3))) unsigned int*)l, 16, 0, 0);
}

// ---------------- fused step: l1(t) + l0(t+1), 128x256 tiles --------------
// 512 blocks: 256 l1 + 256 l0. Block tile 128 rows x [4g][64h]. Waves 2x2.
// 3-buffer LDS, counted vmcnt(6): stage k+2 in flight across raw barriers.
__global__ __launch_bounds__(256, 2) void fused_step(
    int nl1, int nl0,
    const ushort* __restrict__ h0m, const ushort* __restrict__ h1p,
    ushort* __restrict__ h1o, float* __restrict__ c1f,
    const ushort* __restrict__ W1T, const ushort* __restrict__ U1T,
    const float* __restrict__ b1, const uchar* __restrict__ m1B,
    const ushort* __restrict__ Xc, const ushort* __restrict__ h0p,
    ushort* __restrict__ h0o, float* __restrict__ c0f,
    const ushort* __restrict__ W0T, const ushort* __restrict__ U0T,
    const float* __restrict__ b0, const uchar* __restrict__ m0B,
    int tprep, const int* __restrict__ inputs, const float* __restrict__ embed,
    ushort* __restrict__ Xprep) {
  __shared__ __align__(16) ushort smem[36864];  // 3 x (A 4096 + B 8192)
  const int bid = blockIdx.x, tid = threadIdx.x;
  const bool isl1 = bid < nl1;
  const int lbid = isl1 ? bid : bid - nl1;
  const int cid = (lbid & 7) * 32 + (lbid >> 3);  // XCD-chunked
  const int mblk = cid >> 3, nblk = cid & 7;
  const int bm0 = mblk * 128, bh0 = nblk * 64;
  const int rtb = bm0 >> 4;                       // A row-tile base
  const int btb = bh0 >> 4;                       // B h-tile base
  const int w = tid >> 6, l = tid & 63;
  const int wr = w >> 1, wc = w & 1;
  const int fr = l & 15, kq = l >> 4;

  const ushort *A1, *B1, *A2, *B2;
  const uchar* mB;
  const float* bias;
  float* cb;
  ushort* hout;
  int KT1, S1, K1;
  if (isl1) {
    A1 = h0m; B1 = W1T; A2 = h1p; B2 = U1T; mB = m1B; bias = b1;
    cb = c1f; hout = h1o; KT1 = 16; S1 = 16; K1 = 512;
  } else {
    A1 = Xc; B1 = W0T; A2 = h0p; B2 = U0T; mB = m0B; bias = b0;
    cb = c0f; hout = h0o; KT1 = 4; S1 = 4; K1 = 128;
  }
  const int S = S1 + 16;

  auto stg = [&](int s2, ushort* buf) {
    const ushort* Ag; const ushort* Bg; int KT, kt;
    if (s2 < S1) { Ag = A1; Bg = B1; KT = KT1; kt = s2; }
    else         { Ag = A2; Bg = B2; KT = 16;  kt = s2 - S1; }
#pragma unroll
    for (int c2 = 0; c2 < 2; c2++) {
      const int rt = w + c2 * 4;
      gload16(Ag + ((size_t)(rtb + rt) * KT + kt) * 512 + l * 8, buf + rt * 512);
    }
#pragma unroll
    for (int c2 = 0; c2 < 4; c2++) {
      const int ct = w * 4 + c2;
      const int gnt = (ct >> 2) * 32 + btb + (ct & 3);  // gate*32 tiles + h tile
      gload16(Bg + ((size_t)gnt * KT + kt) * 512 + l * 8,
              buf + 4096 + ct * 512);
    }
  };

  // prologue: stage k-steps 0,1
  stg(0, smem);
  stg(1, smem + 12288);

  f32x4 acc[4][8] = {};
  int cur = 0;

#pragma unroll 1
  for (int s = 0; s < S; s++) {
    const bool masked = s < S1;
    uint64_t mq[4][4];
    if (masked) {
      const int kb = s * 32 + kq * 8;
#pragma unroll
      for (int fi = 0; fi < 4; fi++) {
        const int row = bm0 + wr * 64 + fi * 16 + fr;
#pragma unroll
        for (int g = 0; g < 4; g++) {
          const uchar* ap = mB + ((size_t)g * BATCH + row) * K1 + kb;
          asm volatile("global_load_dwordx2 %0, %1, off"
                       : "=v"(mq[fi][g]) : "v"(ap) : "memory");
        }
      }
    }
    if (s + 2 < S) {
      int nb = cur + 2; if (nb >= 3) nb -= 3;
      stg(s + 2, smem + nb * 12288);
    }
    // queue: [G(s+1):6][M(s):16][G(s+2):6] -> vmcnt(6) ensures G(s),M(s) done
    if (s == S - 1) asm volatile("s_waitcnt vmcnt(0)" ::: "memory");
    else            asm volatile("s_waitcnt vmcnt(6)" ::: "memory");
    __builtin_amdgcn_s_barrier();

    const ushort* cbuf = smem + cur * 12288;
    u32x4 af[4];
#pragma unroll
    for (int fi = 0; fi < 4; fi++)
      af[fi] = *(const u32x4*)&cbuf[(wr * 4 + fi) * 512 + l * 8];
#pragma unroll
    for (int g = 0; g < 4; g++) {
      const bf16x8 b0v =
          *(const bf16x8*)&cbuf[4096 + (g * 4 + wc * 2 + 0) * 512 + l * 8];
      const bf16x8 b1v =
          *(const bf16x8*)&cbuf[4096 + (g * 4 + wc * 2 + 1) * 512 + l * 8];
#pragma unroll
      for (int fi = 0; fi < 4; fi++) {
        u32x4 ua = af[fi];
        if (masked) {
          const uint32_t mx = (uint32_t)mq[fi][g];
          const uint32_t my = (uint32_t)(mq[fi][g] >> 32);
          ua.x &= __builtin_amdgcn_perm(mx, mx, 0x01010000u);
          ua.y &= __builtin_amdgcn_perm(mx, mx, 0x03030202u);
          ua.z &= __builtin_amdgcn_perm(my, my, 0x01010000u);
          ua.w &= __builtin_amdgcn_perm(my, my, 0x03030202u);
        }
        const bf16x8 a = __builtin_bit_cast(bf16x8, ua);
        acc[fi][g * 2 + 0] = __builtin_amdgcn_mfma_f32_16x16x32_bf16(
            a, b0v, acc[fi][g * 2 + 0], 0, 0, 0);
        acc[fi][g * 2 + 1] = __builtin_amdgcn_mfma_f32_16x16x32_bf16(
            a, b1v, acc[fi][g * 2 + 1], 0, 0, 0);
      }
    }
    __builtin_amdgcn_s_barrier();  // protect buf reuse (stage s+3 targets cur)
    cur++; if (cur >= 3) cur = 0;
  }

  // ---- epilogue: gates, c in frag-layout blob, h via LDS transpose ----
  float* cbase = cb + ((size_t)cid * 256 + tid) * 32;
  f32x4 cold[8];
#pragma unroll
  for (int q = 0; q < 8; q++) cold[q] = *(const f32x4*)(cbase + q * 4);
  float bi[2], bfv[2], bg[2], bo[2];
#pragma unroll
  for (int hf = 0; hf < 2; hf++) {
    const int h = bh0 + wc * 32 + hf * 16 + fr;
    bi[hf] = bias[h];
    bfv[hf] = bias[512 + h];
    bg[hf] = bias[1024 + h];
    bo[hf] = bias[1536 + h];
  }
  f32x4 cnew[8];
#pragma unroll
  for (int fi = 0; fi < 4; fi++) {
#pragma unroll
    for (int hf = 0; hf < 2; hf++) {
#pragma unroll
      for (int jj = 0; jj < 4; jj++) {
        const float zi = acc[fi][0 + hf][jj] + bi[hf];
        const float zf = acc[fi][2 + hf][jj] + bfv[hf];
        const float zg = acc[fi][4 + hf][jj] + bg[hf];
        const float zo = acc[fi][6 + hf][jj] + bo[hf];
        const float iv = 1.f / (1.f + __expf(-zi));
        const float fv = 1.f / (1.f + __expf(-zf));
        const float gv = fast_tanh(zg);
        const float ov = 1.f / (1.f + __expf(-zo));
        const float cn = fv * cold[fi * 2 + hf][jj] + iv * gv;
        cnew[fi * 2 + hf][jj] = cn;
        const float hn = ov * fast_tanh(cn);
        smem[(wr * 64 + fi * 16 + kq * 4 + jj) * 64 + wc * 32 + hf * 16 + fr] =
            f2bf(hn);
      }
    }
  }
#pragma unroll
  for (int q = 0; q < 8; q++) *(f32x4*)(cbase + q * 4) = cnew[q];
  __syncthreads();

  // tiled h writeback: 1024 chunks (16 tiles of 64)
#pragma unroll
  for (int c2 = 0; c2 < 4; c2++) {
    const int u = c2 * 256 + tid;
    const int t2 = u >> 6, i2 = u & 63;
    const int rt = t2 >> 1, kt2 = t2 & 1;
    const int ck = i2 >> 4, rr = i2 & 15;
    const size_t gt = (size_t)((rtb + rt) * 16 + (bh0 >> 5) + kt2);
    *(bf16x8*)(hout + gt * 512 + ck * 128 + rr * 8) =
        *(const bf16x8*)&smem[(rt * 16 + rr) * 64 + kt2 * 32 + ck * 8];
  }

  // X prep for step tprep (balanced: all 256 l0 blocks, 1 chunk/thread)
  if (!isl1 && tprep >= 0) {
    const int id = lbid * 256 + tid;  // 65536 = 4096 rows x 16 chunks
    const int b = id >> 4, kc = id & 15;
    const int idx = inputs[b * TT + tprep];
    ushort v[8];
#pragma unroll
    for (int j = 0; j < 8; j++) {
      const int kk = kc * 8 + j;
      v[j] = (kk < EMB) ? f2bf(embed[(size_t)idx * EMB + kk]) : (ushort)0;
    }
    *(bf16x8*)(Xprep + TOFF(b, kc * 8, 4)) = *(bf16x8*)v;
  }
}

// ---------------- final projection (tiled h read) -------------------------
__global__ __launch_bounds__(256) void out_kernel(const ushort* __restrict__ h1b,
                                                  const float* __restrict__ Wout,
                                                  const float* __restrict__ bout,
                                                  float* __restrict__ out) {
  const int wid = (blockIdx.x * 256 + threadIdx.x) >> 6;
  const int lane = threadIdx.x & 63;
  if (wid >= BATCH) return;
  const int rt = wid >> 4, rl = wid & 15;
  const int kt = lane >> 2, ch = lane & 3;
  const ushort* p = h1b + (((size_t)(rt * 16 + kt)) << 9) + (ch << 7) + (rl << 3);
  const int kbase = kt * 32 + ch * 8;
  float s = 0.f;
#pragma unroll
  for (int e = 0; e < 8; e++) s += bf2f(p[e]) * Wout[kbase + e];
  for (int off = 32; off; off >>= 1) s += __shfl_down(s, off, 64);
  if (lane == 0) out[wid] = 1.f / (1.f + __expf(-(s + bout[0])));
}

// --------------------------------------------------------------------------
extern "C" void kernel_launch(void* const* d_in, const int* in_sizes, int n_in,
                              void* d_out, int out_size, void* d_ws, size_t ws_size,
                              hipStream_t stream) {
  const int* inputs = (const int*)d_in[0];
  const float* embed = (const float*)d_in[1];
  const float* W0 = (const float*)d_in[2];
  const float* U0 = (const float*)d_in[3];
  const float* b0 = (const float*)d_in[4];
  const float* W1 = (const float*)d_in[5];
  const float* U1 = (const float*)d_in[6];
  const float* b1 = (const float*)d_in[7];
  const float* Wout = (const float*)d_in[8];
  const float* bout = (const float*)d_in[9];
  float* out = (float*)d_out;

  char* ws = (char*)d_ws;
  const size_t MB = 1 << 20;
  float* c0f   = (float*)(ws);              //  8 MB (zero)
  float* c1f   = (float*)(ws + 8 * MB);     //  8 MB (zero)
  ushort* h0b1 = (ushort*)(ws + 16 * MB);   //  4 MB (zero)
  ushort* h1b1 = (ushort*)(ws + 20 * MB);   //  4 MB (zero)
  ushort* h0b0 = (ushort*)(ws + 24 * MB);   //  4 MB
  ushort* h1b0 = (ushort*)(ws + 28 * MB);   //  4 MB
  ushort* X0   = (ushort*)(ws + 32 * MB);   //  1 MB
  ushort* X1   = (ushort*)(ws + 33 * MB);   //  1 MB
  ushort* X2   = (ushort*)(ws + 34 * MB);   //  1 MB
  ushort* W0T  = (ushort*)(ws + 35 * MB);   //  0.5 MB tiled [2048][128]
  ushort* U0T  = (ushort*)(ws + 36 * MB);   //  2 MB   tiled [2048][512]
  ushort* W1T  = (ushort*)(ws + 38 * MB);   //  2 MB
  ushort* U1T  = (ushort*)(ws + 40 * MB);   //  2 MB
  ushort* tmp  = (ushort*)(ws + 42 * MB);   //  2 MB   linear scratch
  uchar* m0B   = (uchar*)(ws + 44 * MB);    //  2 MB   [4][4096][128]
  uchar* m1B   = (uchar*)(ws + 46 * MB);    //  8 MB   [4][4096][512]

  ushort* h0b[2] = {h0b0, h0b1};
  ushort* h1b[2] = {h1b0, h1b1};
  ushort* X[3] = {X0, X1, X2};

  hipMemsetAsync(ws, 0, 24 * MB, stream);   // c0f, c1f, h0b1, h1b1

  masksB<<<8192, 256, 0, stream>>>(m0B, m1B);
  {
    dim3 g0(2048 / 32, K0P / 32), g1(2048 / 32, UNITS / 32);
    convT<<<g0, 256, 0, stream>>>(W0, tmp, EMB, K0P, 1.25f);
    retileB<<<(2048 * K0P / 8) / 256, 256, 0, stream>>>(tmp, W0T, K0P);
    convT<<<g1, 256, 0, stream>>>(U0, tmp, UNITS, UNITS, 1.0f);
    retileB<<<(2048 * UNITS / 8) / 256, 256, 0, stream>>>(tmp, U0T, UNITS);
    convT<<<g1, 256, 0, stream>>>(W1, tmp, UNITS, UNITS, 1.25f);
    retileB<<<(2048 * UNITS / 8) / 256, 256, 0, stream>>>(tmp, W1T, UNITS);
    convT<<<g1, 256, 0, stream>>>(U1, tmp, UNITS, UNITS, 1.0f);
    retileB<<<(2048 * UNITS / 8) / 256, 256, 0, stream>>>(tmp, U1T, UNITS);
  }
  xprep2<<<512, 256, 0, stream>>>(inputs, embed, X0, X1);

  // prologue: l0(t=0) only; h_prev = h0b[1] (zeros); preps X[2] (t=2)
  fused_step<<<256, 256, 0, stream>>>(
      0, 256, h0b[1], h1b[1], h1b[0], c1f, W1T, U1T, b1, m1B,
      X[0], h0b[1], h0b[0], c0f, W0T, U0T, b0, m0B,
      2, inputs, embed, X[2]);

  for (int k = 0; k < TT; k++) {
    const int p = k & 1;
    const int nl0 = (k < TT - 1) ? 256 : 0;
    const int tp = (k + 3 < TT) ? (k + 3) : -1;
    fused_step<<<256 + nl0, 256, 0, stream>>>(
        256, nl0,
        h0b[p], h1b[p ^ 1], h1b[p], c1f, W1T, U1T, b1, m1B,
        X[(k + 1) % 3], h0b[p], h0b[p ^ 1], c0f, W0T, U0T, b0, m0B,
        tp, inputs, embed, X[k % 3]);
  }

  // final h1 written at t=79 -> h1b[1]
  out_kernel<<<BATCH * 64 / 256, 256, 0, stream>>>(h1b[1], Wout, bout, out);
}